// Round 9
// baseline (192.487 us; speedup 1.0000x reference)
//
#include <hip/hip_runtime.h>
#include <math.h>

#define NLEV 5
#define TOPKK 1000
#define NCLS 16
#define NPART 16                 // cand partitions (by chunk id)
#define HP 16u                   // histogram partial copies
#define PART_CAP 256
#define CAND_TOT 2048
#define NCHUNK 3069u             // 785664 / 256
#define HISTSZ (NLEV * 256)      // 1280 u32 per copy

// LLC-coherent accessors: agent-scope relaxed atomics bypass per-XCD L2 and
// serialize at the LLC. All cross-block data uses these; no release/acquire
// fences anywhere (gfx950 fences lower to buffer_wbl2/buffer_inv = full-L2
// writeback/invalidate -- measured ~7us/barrier cost, removed in r7).
__device__ __forceinline__ unsigned g_load(const unsigned* p) {
    return __hip_atomic_load(p, __ATOMIC_RELAXED, __HIP_MEMORY_SCOPE_AGENT);
}
__device__ __forceinline__ unsigned long long g_load64(const unsigned long long* p) {
    return __hip_atomic_load(p, __ATOMIC_RELAXED, __HIP_MEMORY_SCOPE_AGENT);
}
__device__ __forceinline__ void g_store64(unsigned long long* p, unsigned long long v) {
    __hip_atomic_store(p, v, __ATOMIC_RELAXED, __HIP_MEMORY_SCOPE_AGENT);
}

// chunk-index level boundaries: 2304, 2880, 3024, 3060 — divisible by 2, 3
// and 6, so blocks are level-pure for CPB in {2,3,6}.
__device__ __forceinline__ int lev_of_chunk(unsigned c) {
    if (c < 2304u) return 0;
    if (c < 2880u) return 1;
    if (c < 3024u) return 2;
    if (c < 3060u) return 3;
    return 4;
}
__device__ __forceinline__ unsigned lev_base(int l) {   // entry base per level
    unsigned b = 0u;
    if (l == 1) b = 589824u;
    if (l == 2) b = 737280u;
    if (l == 3) b = 774144u;
    if (l == 4) b = 783360u;
    return b;
}
// blocks per level = ceil(level_chunks / CPB); level chunks {2304,576,144,36,9}
template<unsigned CPBV>
__device__ __forceinline__ unsigned lev_expect(int l) {
    unsigned lc = (l == 0) ? 2304u : (l == 1) ? 576u : (l == 2) ? 144u
                : (l == 3) ? 36u : 9u;
    return (lc + CPBV - 1u) / CPBV;
}

struct Ptrs {
    const float* anc[NLEV];
    const float* cls[NLEV];
    const float* reg[NLEV];
};

// order-preserving float32 -> uint32 (larger uint == larger float)
__device__ __forceinline__ unsigned f2key(float f) {
    unsigned u = __float_as_uint(f);
    return (u & 0x80000000u) ? ~u : (u | 0x80000000u);
}

__device__ __forceinline__ float max4(float4 v) {
    return fmaxf(fmaxf(v.x, v.y), fmaxf(v.z, v.w));
}

// ---- per-level completion sync (replaces grid barriers) ------------------
// sync[round][lev] = 16 cachelines of counters (u32 idx: round*1280 +
// lev*256 + line*16). A block's leader adds 1 to line (b&15) AFTER
// __syncthreads() drained vmcnt(0) (=> all its LLC-bound atomics acked);
// waiters poll the 16-line sum against the exact per-level block count.
// Levels are independent pipelines -> no cross-level straggler coupling,
// and detection is one LLC poll instead of a monitor->relay chain.
__device__ __forceinline__ void lev_arrive(unsigned* sync, int round, int lev) {
    if (threadIdx.x == 0)
        atomicAdd(&sync[(unsigned)round * 1280u + (unsigned)lev * 256u
                        + (blockIdx.x & 15u) * 16u], 1u);
}
__device__ __forceinline__ void lev_wait(unsigned* sync, int round, int lev,
                                         unsigned expect) {
    if (threadIdx.x == 0) {
        const unsigned* p = sync + (unsigned)round * 1280u + (unsigned)lev * 256u;
        for (;;) {
            unsigned s = 0;
            #pragma unroll
            for (int i = 0; i < 16; i++) s += g_load(p + i * 16);
            if (s == expect) break;
            __builtin_amdgcn_s_sleep(2);
        }
    }
    __syncthreads();    // also fences: no thread reads shared data early
}

// suffix-select over 256 bins (bin == threadIdx) via wave shuffles.
// Finds bin holding the rem-th largest; aux[0]=bin, aux[1]=remainder.
// (verbatim r5-r8 core, absmax-0 verified)
__device__ __forceinline__ void sel256(unsigned c, unsigned rem,
                                       unsigned* wsum, unsigned* aux) {
    int t = threadIdx.x, lane = t & 63, wv = t >> 6;
    unsigned s = c;                          // suffix-sum over lanes >= mine
    #pragma unroll
    for (int d = 1; d < 64; d <<= 1) {
        unsigned o = __shfl_down(s, d, 64);
        if (lane + d < 64) s += o;
    }
    if (lane == 0) wsum[wv] = s;             // wave total
    __syncthreads();
    unsigned incl = s;                       // + totals of higher-bin waves
    #pragma unroll
    for (int w2 = 1; w2 < 4; w2++) if (wv + w2 < 4) incl += wsum[wv + w2];
    unsigned above = incl - c;
    if (above < rem && rem <= incl) {        // exactly one winner thread
        aux[0] = (unsigned)t;
        aux[1] = rem - above;
    }
    __syncthreads();
}

// One persistent kernel: level-pure blocks, keys in registers, per-level
// completion sync, LLC-scope cross-block data. Selection semantics
// bit-identical to the verified round-0 kernel.
template<unsigned CPBV, unsigned NBV>
__global__ __launch_bounds__(256, 2) void k_fused(Ptrs p, unsigned* histA,
        unsigned* histB, unsigned* cnt, unsigned* sync,
        unsigned long long* cand, float* out) {
    __shared__ unsigned long long lbuf[CAND_TOT];   // 16 KB (rank phase only)
    __shared__ unsigned hh[256];
    __shared__ unsigned wsum[4];
    __shared__ unsigned aux[33];

    const unsigned b = blockIdx.x;
    const int t = threadIdx.x;
    const unsigned c0 = b * CPBV;
    const int lev = lev_of_chunk(c0);
    const unsigned ebase = lev_base(lev);
    const unsigned expect = lev_expect<CPBV>(lev);

    // ---- Phase A1: all loads + fmax first (no LDS ops in the way) ----
    unsigned keys[CPBV];
    #pragma unroll
    for (unsigned j = 0; j < CPBV; j++) {
        unsigned ch = c0 + j;
        unsigned k = 0u;
        if (ch < NCHUNK) {
            unsigned loc = ch * 256u + (unsigned)t - ebase;
            const float4* cp = (const float4*)(p.cls[lev]) + (size_t)loc * 4;
            float4 v0 = cp[0], v1 = cp[1], v2 = cp[2], v3 = cp[3];
            float m = fmaxf(fmaxf(max4(v0), max4(v1)), fmaxf(max4(v2), max4(v3)));
            k = f2key(m);
        }
        keys[j] = k;
    }
    // ---- Phase A2: block byte-1 hist; one flush into 1-of-16 copies ----
    hh[t] = 0u;
    __syncthreads();
    #pragma unroll
    for (unsigned j = 0; j < CPBV; j++)
        if (c0 + j < NCHUNK) atomicAdd(&hh[keys[j] >> 24], 1u);
    __syncthreads();
    {
        unsigned v = hh[t];
        if (v) atomicAdd(&histA[(b & (HP - 1u)) * HISTSZ
                                + (unsigned)lev * 256u + (unsigned)t], v);
    }
    __syncthreads();                         // drains vmcnt: histA adds acked
    lev_arrive(sync, 0, lev);
    lev_wait(sync, 0, lev, expect);

    // ---- Select byte-1 for OWN level only (LLC loads; level-pure) ----
    unsigned cA = 0;
    #pragma unroll
    for (unsigned pp = 0; pp < HP; pp++)
        cA += g_load(histA + pp * HISTSZ + (unsigned)lev * 256u + (unsigned)t);
    sel256(cA, TOPKK, wsum, aux);
    unsigned binA = aux[0], remA = aux[1];
    __syncthreads();

    // ---- Phase C: byte-2 hist of keys matching byte-1 prefix ----
    hh[t] = 0u;
    __syncthreads();
    #pragma unroll
    for (unsigned j = 0; j < CPBV; j++) {
        unsigned k = keys[j];
        if ((c0 + j) < NCHUNK && (k >> 24) == binA)
            atomicAdd(&hh[(k >> 16) & 0xFFu], 1u);
    }
    __syncthreads();
    {
        unsigned v = hh[t];
        if (v) atomicAdd(&histB[(b & (HP - 1u)) * HISTSZ
                                + (unsigned)lev * 256u + (unsigned)t], v);
    }
    __syncthreads();                         // drains vmcnt: histB adds acked
    lev_arrive(sync, 1, lev);
    lev_wait(sync, 1, lev, expect);

    // ---- Select byte-2 -> 16-bit threshold (identical semantics) ----
    unsigned cB = 0;
    #pragma unroll
    for (unsigned pp = 0; pp < HP; pp++)
        cB += g_load(histB + pp * HISTSZ + (unsigned)lev * 256u + (unsigned)t);
    sel256(cB, remA, wsum, aux);
    unsigned thresh = (binA << 24) | (aux[0] << 16);
    __syncthreads();

    // ---- Phase E: compact candidates (all stores LLC-scope) ----
    #pragma unroll
    for (unsigned j = 0; j < CPBV; j++) {
        unsigned ch = c0 + j;
        unsigned k = keys[j];
        if (ch < NCHUNK && k >= thresh) {
            unsigned loc = ch * 256u + (unsigned)t - ebase;
            unsigned part = ch & (NPART - 1u);
            unsigned slot = atomicAdd(&cnt[(lev * NPART + part) * 16u], 1u);
            if (slot < PART_CAP)
                g_store64(&cand[((size_t)(lev * NPART + part)) * PART_CAP + slot],
                          ((unsigned long long)k << 32) | (unsigned)(~loc));
        }
    }
    __syncthreads();                         // drains vmcnt: cand stores acked
    lev_arrive(sync, 2, lev);

    // ---- Rankers wait only on their TARGET level's completion ----
    bool ranker = b < (unsigned)(NLEV * 8);
    if (!ranker) return;
    int rl = (int)(b >> 3);
    lev_wait(sync, 2, rl, lev_expect<CPBV>(rl));

    // ---- Phase F: rank-by-counting + emit (verified round-0 logic) ----
    const float MAXD = 4.135166556742356f;   // log(1000/16)
    int l = rl;
    unsigned sl = b & 7u;

    if (t < NPART) {
        unsigned cc = g_load(cnt + (l * NPART + t) * 16u);
        aux[t] = (cc > PART_CAP) ? PART_CAP : cc;
    }
    __syncthreads();
    if (t == 0) {
        unsigned o = 0;
        for (int pp = 0; pp < NPART; pp++) { aux[16 + pp] = o; o += aux[pp]; }
        aux[32] = (o > CAND_TOT) ? CAND_TOT : o;
    }
    __syncthreads();
    unsigned n = aux[32];
    for (int pp = 0; pp < NPART; pp++) {
        unsigned cc = aux[pp], o = aux[16 + pp];
        for (unsigned e = (unsigned)t; e < cc; e += 256u) {
            unsigned dst = o + e;
            if (dst < CAND_TOT)
                lbuf[dst] = g_load64(&cand[((size_t)(l * NPART + pp)) * PART_CAP + e]);
        }
    }
    __syncthreads();

    unsigned j = sl * 256u + (unsigned)t;
    if (j >= n) return;
    unsigned long long my = lbuf[j];
    unsigned rank = 0;
    #pragma unroll 8
    for (unsigned q = 0; q < n; q++) rank += (lbuf[q] > my) ? 1u : 0u;
    if (rank >= TOPKK) return;

    unsigned idx = ~((unsigned)(my & 0xFFFFFFFFull));
    float4 an = ((const float4*)p.anc[l])[idx];
    float4 dd = ((const float4*)p.reg[l])[(size_t)idx * 2];
    float w = an.z - an.x, h = an.w - an.y;
    float cx = an.x + 0.5f * w, cy = an.y + 0.5f * h;
    float pcx = cx + dd.x * w, pcy = cy + dd.y * h;
    float pw = w * expf(fminf(dd.z, MAXD));
    float ph = h * expf(fminf(dd.w, MAXD));
    float bx = pcx - 0.5f * pw, by = pcy - 0.5f * ph;
    float bz = pcx + 0.5f * pw, bw = pcy + 0.5f * ph;

    const float4* cp = (const float4*)(p.cls[l]) + (size_t)idx * 4;
    float sg[16];
    #pragma unroll
    for (int g = 0; g < 4; g++) {
        float4 v = cp[g];
        sg[4 * g + 0] = 1.0f / (1.0f + expf(-v.x));
        sg[4 * g + 1] = 1.0f / (1.0f + expf(-v.y));
        sg[4 * g + 2] = 1.0f / (1.0f + expf(-v.z));
        sg[4 * g + 3] = 1.0f / (1.0f + expf(-v.w));
    }
    // 16 rows of [bx,by,bz,bw,score,tag] == 24 float4s, 384B contiguous
    float4* q = (float4*)(out + (size_t)(l * TOPKK + rank) * (NCLS * 6));
    #pragma unroll
    for (int g = 0; g < 8; g++) {
        float ta = (float)(2 * g + 1), tb = (float)(2 * g + 2);
        q[3 * g + 0] = make_float4(bx, by, bz, bw);
        q[3 * g + 1] = make_float4(sg[2 * g], ta, bx, by);
        q[3 * g + 2] = make_float4(bz, bw, sg[2 * g + 1], tb);
    }
}

extern "C" void kernel_launch(void* const* d_in, const int* in_sizes, int n_in,
                              void* d_out, int out_size, void* d_ws, size_t ws_size,
                              hipStream_t stream) {
    (void)in_sizes; (void)n_in; (void)out_size; (void)ws_size;
    Ptrs p;
    for (int l = 0; l < NLEV; l++) {
        p.anc[l] = (const float*)d_in[3 * l + 0];
        p.cls[l] = (const float*)d_in[3 * l + 1];
        p.reg[l] = (const float*)d_in[3 * l + 2];
    }

    // Shape choice gated by the runtime occupancy calculator (cached,
    // host-only queries -> graph-capture safe). Prefer 1535 blocks (6/CU,
    // max TLP for phase A), else the r8-verified 1023, else the r7 512.
    static int s_which = -1;
    if (s_which < 0) {
        int bpcu = 0;
        if (hipOccupancyMaxActiveBlocksPerMultiprocessor(
                &bpcu, (const void*)k_fused<2u, 1535u>, 256, 0) != hipSuccess)
            bpcu = 0;
        int dev = 0, ncu = 0;
        (void)hipGetDevice(&dev);
        if (hipDeviceGetAttribute(&ncu, hipDeviceAttributeMultiprocessorCount,
                                  dev) != hipSuccess || ncu < 1)
            ncu = 0;
        long long cap = (long long)bpcu * (long long)ncu;
        s_which = (bpcu >= 6 && cap >= 1535) ? 2
                : (bpcu >= 4 && cap >= 1023) ? 1 : 0;
    }

    char* w = (char*)d_ws;
    // layout (bytes):
    //   histA : 0      .. 81920   \   16 copies x 5120 B
    //   histB : 81920  .. 163840   }  one contiguous memset (184320 B)
    //   cnt   : 163840 .. 168960   }  80 counters x 64 B (1 line each)
    //   sync  : 168960 .. 184320  /   3 rounds x 5 levels x 16 lines
    //   cand  : 184320 .. 348160      (guarded by cnt, no memset)
    unsigned* histA = (unsigned*)w;
    unsigned* histB = (unsigned*)(w + 81920);
    unsigned* cnt   = (unsigned*)(w + 163840);
    unsigned* sync  = (unsigned*)(w + 168960);
    unsigned long long* cand = (unsigned long long*)(w + 184320);
    float* out = (float*)d_out;

    (void)hipMemsetAsync(w, 0, 184320, stream);
    if (s_which == 2) {
        k_fused<2u, 1535u><<<dim3(1535), dim3(256), 0, stream>>>(
            p, histA, histB, cnt, sync, cand, out);
    } else if (s_which == 1) {
        k_fused<3u, 1023u><<<dim3(1023), dim3(256), 0, stream>>>(
            p, histA, histB, cnt, sync, cand, out);
    } else {
        k_fused<6u, 512u><<<dim3(512), dim3(256), 0, stream>>>(
            p, histA, histB, cnt, sync, cand, out);
    }
}

// Round 10
// 163.387 us; speedup vs baseline: 1.1781x; 1.1781x over previous
//
#include <hip/hip_runtime.h>
#include <math.h>

#define NLEV 5
#define TOPKK 1000
#define NCLS 16
#define NPART 16                 // cand partitions (by chunk id)
#define HP 16u                   // histogram partial copies
#define PART_CAP 256
#define CAND_TOT 2048
#define NCHUNK 3069u             // 785664 / 256
#define HISTSZ (NLEV * 256)      // 1280 u32 per copy
#define BAR_U32 5120u            // per sync instance: flags[0..1023], go @1024+b*4

// LLC-coherent accessors: agent-scope relaxed atomics bypass per-XCD L2 and
// serialize at the LLC. All cross-block data uses these; no release/acquire
// fences anywhere (gfx950 fences lower to buffer_wbl2/buffer_inv = full-L2
// writeback/invalidate -- ~7us/barrier, removed in r7).
__device__ __forceinline__ unsigned g_load(const unsigned* p) {
    return __hip_atomic_load(p, __ATOMIC_RELAXED, __HIP_MEMORY_SCOPE_AGENT);
}
__device__ __forceinline__ unsigned long long g_load64(const unsigned long long* p) {
    return __hip_atomic_load(p, __ATOMIC_RELAXED, __HIP_MEMORY_SCOPE_AGENT);
}
__device__ __forceinline__ void g_store(unsigned* p, unsigned v) {
    __hip_atomic_store(p, v, __ATOMIC_RELAXED, __HIP_MEMORY_SCOPE_AGENT);
}
__device__ __forceinline__ void g_store64(unsigned long long* p, unsigned long long v) {
    __hip_atomic_store(p, v, __ATOMIC_RELAXED, __HIP_MEMORY_SCOPE_AGENT);
}

// chunk-index level boundaries: 2304, 2880, 3024, 3060 — divisible by 3 and
// 6, so blocks are level-pure for CPB in {3,6}.
__device__ __forceinline__ int lev_of_chunk(unsigned c) {
    if (c < 2304u) return 0;
    if (c < 2880u) return 1;
    if (c < 3024u) return 2;
    if (c < 3060u) return 3;
    return 4;
}
__device__ __forceinline__ unsigned lev_base(int l) {   // entry base per level
    unsigned b = 0u;
    if (l == 1) b = 589824u;
    if (l == 2) b = 737280u;
    if (l == 3) b = 774144u;
    if (l == 4) b = 783360u;
    return b;
}

struct Ptrs {
    const float* anc[NLEV];
    const float* cls[NLEV];
    const float* reg[NLEV];
};

// order-preserving float32 -> uint32 (larger uint == larger float)
__device__ __forceinline__ unsigned f2key(float f) {
    unsigned u = __float_as_uint(f);
    return (u & 0x80000000u) ? ~u : (u | 0x80000000u);
}

__device__ __forceinline__ float max4(float4 v) {
    return fmaxf(fmaxf(v.x, v.y), fmaxf(v.z, v.w));
}

// ---- fence-free store-based grid barrier (r7/r8-verified design, ILP-fixed)
//   flags[b]   = inst[b]             one word per block, relaxed store
//   go[b]      = inst[1024 + b*4]    PRIVATE go word per block (16B stride)
// ORDERING: __syncthreads() before arrival drains vmcnt(0) in every wave, so
// all the block's LLC-bound atomics complete before the flag store; all
// cross-block data moves via agent-scope atomics (LLC = serialization
// point) => flag-observed implies data-visible. No wbl2/inv anywhere.
__device__ __forceinline__ void bar_arrive(unsigned* inst) {
    if (threadIdx.x == 0) g_store(inst + blockIdx.x, 1u);
}

// block 0 only, ALL threads participate. Sweep uses INDEPENDENT loads (all
// issued before any use -> one vmcnt wait, not a serialized chain).
template<unsigned NBV>
__device__ __forceinline__ void bar_monitor_fanout(unsigned* inst, unsigned* wsh) {
    const int t = threadIdx.x;
    for (;;) {
        unsigned f0 = g_load(inst + t);                                   // t < 256 <= NBV
        unsigned f1 = (256u + (unsigned)t < NBV) ? g_load(inst + 256 + t) : 1u;
        unsigned f2 = (NBV > 512u && 512u + (unsigned)t < NBV) ? g_load(inst + 512 + t) : 1u;
        unsigned f3 = (NBV > 768u && 768u + (unsigned)t < NBV) ? g_load(inst + 768 + t) : 1u;
        unsigned all = f0 & f1 & f2 & f3;            // flags are 0/1
        unsigned long long bal = __ballot(all != 0u);
        if ((t & 63) == 0) wsh[t >> 6] = (bal == 0xFFFFFFFFFFFFFFFFull) ? 1u : 0u;
        __syncthreads();
        bool done = wsh[0] && wsh[1] && wsh[2] && wsh[3];
        __syncthreads();
        if (done) break;
        __builtin_amdgcn_s_sleep(1);
    }
    for (unsigned idx = (unsigned)t; idx < NBV; idx += 256u)   // private go words
        g_store(inst + 1024u + idx * 4u, 1u);
}

__device__ __forceinline__ void bar_waitgo(unsigned* inst) {
    while (!g_load(inst + 1024u + blockIdx.x * 4u))
        __builtin_amdgcn_s_sleep(2);
}

template<unsigned NBV>
__device__ __forceinline__ void gridbar(unsigned* inst, unsigned* wsh) {
    __syncthreads();                       // drains vmcnt in all waves
    bar_arrive(inst);
    if (blockIdx.x == 0) {
        bar_monitor_fanout<NBV>(inst, wsh);
    } else if (threadIdx.x == 0) {
        bar_waitgo(inst);
    }
    __syncthreads();
}

// suffix-select over 256 bins (bin == threadIdx) via wave shuffles.
// Finds bin holding the rem-th largest; aux[0]=bin, aux[1]=remainder.
// (verbatim r5-r8 core, absmax-0 verified)
__device__ __forceinline__ void sel256(unsigned c, unsigned rem,
                                       unsigned* wsum, unsigned* aux) {
    int t = threadIdx.x, lane = t & 63, wv = t >> 6;
    unsigned s = c;                          // suffix-sum over lanes >= mine
    #pragma unroll
    for (int d = 1; d < 64; d <<= 1) {
        unsigned o = __shfl_down(s, d, 64);
        if (lane + d < 64) s += o;
    }
    if (lane == 0) wsum[wv] = s;             // wave total
    __syncthreads();
    unsigned incl = s;                       // + totals of higher-bin waves
    #pragma unroll
    for (int w2 = 1; w2 < 4; w2++) if (wv + w2 < 4) incl += wsum[wv + w2];
    unsigned above = incl - c;
    if (above < rem && rem <= incl) {        // exactly one winner thread
        aux[0] = (unsigned)t;
        aux[1] = rem - above;
    }
    __syncthreads();
}

// ILP copy-sum: issue all HP hist-copy loads before summing (one vmcnt wait
// instead of a 16-deep serialized LLC chain -- the r9 lesson).
__device__ __forceinline__ unsigned hist_sum(const unsigned* hist, int lev) {
    unsigned vv[HP];
    #pragma unroll
    for (unsigned pp = 0; pp < HP; pp++)
        vv[pp] = g_load(hist + pp * HISTSZ + (unsigned)lev * 256u
                        + (unsigned)threadIdx.x);
    unsigned s = 0;
    #pragma unroll
    for (unsigned pp = 0; pp < HP; pp++) s += vv[pp];
    return s;
}

// One persistent kernel: level-pure blocks, keys in registers, fence-free
// barriers, LLC-scope cross-block data, ILP-fixed LLC access, coalesced
// phase A. Selection semantics bit-identical to the verified round-0 kernel.
template<unsigned CPBV, unsigned NBV>
__global__ __launch_bounds__(256, 2) void k_fused(Ptrs p, unsigned* histA,
        unsigned* histB, unsigned* cnt, unsigned* bar,
        unsigned long long* cand, float* out) {
    __shared__ unsigned long long lbuf[CAND_TOT];   // 16 KB (rank phase only)
    __shared__ unsigned hh[256];
    __shared__ unsigned wsum[4];
    __shared__ unsigned wsh[4];
    __shared__ unsigned aux[33];

    const unsigned b = blockIdx.x;
    const int t = threadIdx.x;
    const unsigned c0 = b * CPBV;
    const int lev = lev_of_chunk(c0);
    const unsigned ebase = lev_base(lev);
    unsigned* bar0 = bar;
    unsigned* bar1 = bar + BAR_U32;
    unsigned* bar2 = bar + 2u * BAR_U32;

    // ---- Phase A1: COALESCED loads + 4-lane shuffle max-reduce ----
    // Entry e owns 16 floats = 4 float4s. Thread t loads float4 #(g*256+t)
    // of the chunk (16B lane stride -> 1KB/wave-instruction, fully
    // coalesced, vs 64B stride before). float4 g*256+t belongs to entry
    // g*64 + (t>>2); a 2-step shfl_xor max within each 4-lane group yields
    // that entry's max in all 4 lanes; thread t keeps g = t&3, i.e. entry
    // eloc = (t&3)*64 + (t>>2)  (bijection; hist is permutation-invariant,
    // compact stores loc explicitly -> output bit-identical).
    unsigned keys[CPBV];
    const float4* f4p = (const float4*)(p.cls[lev]);
    #pragma unroll
    for (unsigned j = 0; j < CPBV; j++) {
        unsigned ch = c0 + j;
        unsigned k = 0u;
        if (ch < NCHUNK) {                     // always true for CPB=3 shape
            unsigned base4 = (ch * 256u - ebase) * 4u;
            float4 a0 = f4p[base4 + 0u * 256u + (unsigned)t];
            float4 a1 = f4p[base4 + 1u * 256u + (unsigned)t];
            float4 a2 = f4p[base4 + 2u * 256u + (unsigned)t];
            float4 a3 = f4p[base4 + 3u * 256u + (unsigned)t];
            float m0 = max4(a0), m1 = max4(a1), m2 = max4(a2), m3 = max4(a3);
            m0 = fmaxf(m0, __shfl_xor(m0, 1, 64));
            m0 = fmaxf(m0, __shfl_xor(m0, 2, 64));
            m1 = fmaxf(m1, __shfl_xor(m1, 1, 64));
            m1 = fmaxf(m1, __shfl_xor(m1, 2, 64));
            m2 = fmaxf(m2, __shfl_xor(m2, 1, 64));
            m2 = fmaxf(m2, __shfl_xor(m2, 2, 64));
            m3 = fmaxf(m3, __shfl_xor(m3, 1, 64));
            m3 = fmaxf(m3, __shfl_xor(m3, 2, 64));
            int g = t & 3;
            float mm = (g == 0) ? m0 : (g == 1) ? m1 : (g == 2) ? m2 : m3;
            k = f2key(mm);
        }
        keys[j] = k;
    }
    // ---- Phase A2: block byte-1 hist; one flush into 1-of-16 copies ----
    hh[t] = 0u;
    __syncthreads();
    #pragma unroll
    for (unsigned j = 0; j < CPBV; j++)
        if (c0 + j < NCHUNK) atomicAdd(&hh[keys[j] >> 24], 1u);
    __syncthreads();
    {
        unsigned v = hh[t];
        if (v) atomicAdd(&histA[(b & (HP - 1u)) * HISTSZ
                                + (unsigned)lev * 256u + (unsigned)t], v);
    }
    gridbar<NBV>(bar0, wsh);

    // ---- Select byte-1 for OWN level only (ILP copy-sum) ----
    sel256(hist_sum(histA, lev), TOPKK, wsum, aux);
    unsigned binA = aux[0], remA = aux[1];
    __syncthreads();

    // ---- Phase C: byte-2 hist of keys matching byte-1 prefix ----
    hh[t] = 0u;
    __syncthreads();
    #pragma unroll
    for (unsigned j = 0; j < CPBV; j++) {
        unsigned k = keys[j];
        if ((c0 + j) < NCHUNK && (k >> 24) == binA)
            atomicAdd(&hh[(k >> 16) & 0xFFu], 1u);
    }
    __syncthreads();
    {
        unsigned v = hh[t];
        if (v) atomicAdd(&histB[(b & (HP - 1u)) * HISTSZ
                                + (unsigned)lev * 256u + (unsigned)t], v);
    }
    gridbar<NBV>(bar1, wsh);

    // ---- Select byte-2 -> 16-bit threshold (identical semantics) ----
    sel256(hist_sum(histB, lev), remA, wsum, aux);
    unsigned thresh = (binA << 24) | (aux[0] << 16);
    __syncthreads();

    // ---- Phase E: compact candidates (loc uses the phase-A permutation) ----
    const unsigned eloc = (((unsigned)t & 3u) << 6) | ((unsigned)t >> 2);
    #pragma unroll
    for (unsigned j = 0; j < CPBV; j++) {
        unsigned ch = c0 + j;
        unsigned k = keys[j];
        if (ch < NCHUNK && k >= thresh) {
            unsigned loc = ch * 256u - ebase + eloc;
            unsigned part = ch & (NPART - 1u);
            unsigned slot = atomicAdd(&cnt[(lev * NPART + part) * 16u], 1u);
            if (slot < PART_CAP)
                g_store64(&cand[((size_t)(lev * NPART + part)) * PART_CAP + slot],
                          ((unsigned long long)k << 32) | (unsigned)(~loc));
        }
    }

    // ---- Exit-flag: everyone arrives; only rank blocks (0..39) wait ----
    bool ranker = b < (unsigned)(NLEV * 8);
    __syncthreads();                       // drains vmcnt (cand stores acked)
    bar_arrive(bar2);
    if (b == 0) {
        bar_monitor_fanout<NBV>(bar2, wsh);
    } else if (ranker) {
        if (t == 0) bar_waitgo(bar2);
    } else {
        return;
    }
    __syncthreads();

    // ---- Phase F: rank-by-counting + emit (verified round-0 logic;
    //      staging via batched independent LLC loads) ----
    const float MAXD = 4.135166556742356f;   // log(1000/16)
    int l = (int)(b >> 3);
    unsigned sl = b & 7u;

    if (t < NPART) {
        unsigned cc = g_load(cnt + (l * NPART + t) * 16u);
        aux[t] = (cc > PART_CAP) ? PART_CAP : cc;
    }
    __syncthreads();
    if (t == 0) {
        unsigned o = 0;
        for (int pp = 0; pp < NPART; pp++) { aux[16 + pp] = o; o += aux[pp]; }
        aux[32] = (o > CAND_TOT) ? CAND_TOT : o;
    }
    __syncthreads();
    unsigned n = aux[32];
    {
        // cc <= PART_CAP == 256 -> each thread handles at most entry #t of
        // each part: 16 guarded INDEPENDENT loads, then 16 LDS stores.
        unsigned long long tv[NPART];
        unsigned vok = 0u;
        #pragma unroll
        for (int pp = 0; pp < NPART; pp++) {
            bool ok = (unsigned)t < aux[pp];
            if (ok) tv[pp] = g_load64(&cand[((size_t)(l * NPART + pp)) * PART_CAP
                                            + (unsigned)t]);
            vok |= ok ? (1u << pp) : 0u;
        }
        #pragma unroll
        for (int pp = 0; pp < NPART; pp++) {
            if (vok & (1u << pp)) {
                unsigned dst = aux[16 + pp] + (unsigned)t;
                if (dst < CAND_TOT) lbuf[dst] = tv[pp];
            }
        }
    }
    __syncthreads();

    unsigned j = sl * 256u + (unsigned)t;
    if (j >= n) return;
    unsigned long long my = lbuf[j];
    unsigned rank = 0;
    #pragma unroll 8
    for (unsigned q = 0; q < n; q++) rank += (lbuf[q] > my) ? 1u : 0u;
    if (rank >= TOPKK) return;

    unsigned idx = ~((unsigned)(my & 0xFFFFFFFFull));
    float4 an = ((const float4*)p.anc[l])[idx];
    float4 dd = ((const float4*)p.reg[l])[(size_t)idx * 2];
    float w = an.z - an.x, h = an.w - an.y;
    float cx = an.x + 0.5f * w, cy = an.y + 0.5f * h;
    float pcx = cx + dd.x * w, pcy = cy + dd.y * h;
    float pw = w * expf(fminf(dd.z, MAXD));
    float ph = h * expf(fminf(dd.w, MAXD));
    float bx = pcx - 0.5f * pw, by = pcy - 0.5f * ph;
    float bz = pcx + 0.5f * pw, bw = pcy + 0.5f * ph;

    const float4* cp = (const float4*)(p.cls[l]) + (size_t)idx * 4;
    float sg[16];
    #pragma unroll
    for (int g = 0; g < 4; g++) {
        float4 v = cp[g];
        sg[4 * g + 0] = 1.0f / (1.0f + expf(-v.x));
        sg[4 * g + 1] = 1.0f / (1.0f + expf(-v.y));
        sg[4 * g + 2] = 1.0f / (1.0f + expf(-v.z));
        sg[4 * g + 3] = 1.0f / (1.0f + expf(-v.w));
    }
    // 16 rows of [bx,by,bz,bw,score,tag] == 24 float4s, 384B contiguous
    float4* q = (float4*)(out + (size_t)(l * TOPKK + rank) * (NCLS * 6));
    #pragma unroll
    for (int g = 0; g < 8; g++) {
        float ta = (float)(2 * g + 1), tb = (float)(2 * g + 2);
        q[3 * g + 0] = make_float4(bx, by, bz, bw);
        q[3 * g + 1] = make_float4(sg[2 * g], ta, bx, by);
        q[3 * g + 2] = make_float4(bz, bw, sg[2 * g + 1], tb);
    }
}

extern "C" void kernel_launch(void* const* d_in, const int* in_sizes, int n_in,
                              void* d_out, int out_size, void* d_ws, size_t ws_size,
                              hipStream_t stream) {
    (void)in_sizes; (void)n_in; (void)out_size; (void)ws_size;
    Ptrs p;
    for (int l = 0; l < NLEV; l++) {
        p.anc[l] = (const float*)d_in[3 * l + 0];
        p.cls[l] = (const float*)d_in[3 * l + 1];
        p.reg[l] = (const float*)d_in[3 * l + 2];
    }

    // Prefer the r8-verified 1023-block shape (4/CU) if the runtime
    // occupancy calculator guarantees residency; else the r7-verified 512.
    static int s_which = -1;
    if (s_which < 0) {
        int bpcu = 0;
        if (hipOccupancyMaxActiveBlocksPerMultiprocessor(
                &bpcu, (const void*)k_fused<3u, 1023u>, 256, 0) != hipSuccess)
            bpcu = 0;
        int dev = 0, ncu = 0;
        (void)hipGetDevice(&dev);
        if (hipDeviceGetAttribute(&ncu, hipDeviceAttributeMultiprocessorCount,
                                  dev) != hipSuccess || ncu < 1)
            ncu = 0;
        s_which = (bpcu >= 4 && (long long)bpcu * ncu >= 1023) ? 1 : 0;
    }

    char* w = (char*)d_ws;
    // layout (bytes):
    //   histA : 0      .. 81920   \   16 copies x 5120 B
    //   histB : 81920  .. 163840   }  one contiguous memset (230400 B)
    //   cnt   : 163840 .. 168960   }  80 counters x 64 B (1 line each)
    //   bar   : 168960 .. 230400  /   3 one-shot sets x 20480 B
    //   cand  : 230400 .. 394240      (guarded by cnt, no memset)
    unsigned* histA = (unsigned*)w;
    unsigned* histB = (unsigned*)(w + 81920);
    unsigned* cnt   = (unsigned*)(w + 163840);
    unsigned* bar   = (unsigned*)(w + 168960);
    unsigned long long* cand = (unsigned long long*)(w + 230400);
    float* out = (float*)d_out;

    (void)hipMemsetAsync(w, 0, 230400, stream);
    if (s_which == 1) {
        k_fused<3u, 1023u><<<dim3(1023), dim3(256), 0, stream>>>(
            p, histA, histB, cnt, bar, cand, out);
    } else {
        k_fused<6u, 512u><<<dim3(512), dim3(256), 0, stream>>>(
            p, histA, histB, cnt, bar, cand, out);
    }
}